// Round 5
// baseline (196.494 us; speedup 1.0000x reference)
//
#include <hip/hip_runtime.h>
#include <hip/hip_bf16.h>

typedef unsigned short u16;
typedef unsigned int u32;
typedef __attribute__((ext_vector_type(8))) short short8;
typedef __attribute__((ext_vector_type(4))) float floatx4;

#define NU 16384
#define DIM 256
#define WIN 160               // 32-row block window: 32 + 2*64
#define YST 264               // Y LDS stride (u16): conflict-free, 16B-mult
#define AST 168               // Am LDS stride (u16): conflict-free, 16B-mult

// ws layout (u16 offsets)
#define XHo 0u
#define XLo 4194304u
#define XRo 8388608u
#define ST0 12582912u
#define STROW 16512u          // 64 guard + 16384 + 64 guard
#define STMAT 4227072u        // 256 * STROW
#define WH0o 25264128u        // ST0 + 3*STMAT
#define WL0o 25329664u
#define WRo  25395200u        // 3 mats x 65536

__device__ __forceinline__ u16 bfh(float v) {            // truncate to bf16
  return (u16)(__float_as_uint(v) >> 16);
}
__device__ __forceinline__ float bup(u16 u) {
  return __uint_as_float(((u32)u) << 16);
}
__device__ __forceinline__ u16 bfrn(float v) {           // round-nearest-even
  u32 u = __float_as_uint(v);
  return (u16)((u + 0x7fffu + ((u >> 16) & 1u)) >> 16);
}

// ---------------------------------------------------------------------------
// xprep: xh/xl (split) + xr (rounded) bf16 copies of x.
// ---------------------------------------------------------------------------
__global__ __launch_bounds__(256) void xprep(const float* __restrict__ x,
                                             u16* __restrict__ ws) {
  int idx = (blockIdx.x * 256 + threadIdx.x) * 4;
  float4 v = *(const float4*)(x + idx);
  float a[4] = {v.x, v.y, v.z, v.w};
  u16 h[4], l[4], r[4];
#pragma unroll
  for (int q = 0; q < 4; ++q) {
    h[q] = bfh(a[q]);
    l[q] = bfh(a[q] - bup(h[q]));
    r[q] = bfrn(a[q]);
  }
  *(ushort4*)(ws + XHo + idx) = make_ushort4(h[0], h[1], h[2], h[3]);
  *(ushort4*)(ws + XLo + idx) = make_ushort4(l[0], l[1], l[2], l[3]);
  *(ushort4*)(ws + XRo + idx) = make_ushort4(r[0], r[1], r[2], r[3]);
}

// ---------------------------------------------------------------------------
// wpgz: blocks 0-31 = weight imaging; blocks 32-127 = S^T guard zeroing.
// Images are [s][n][k] (k contiguous within 32-chunk s).
// ---------------------------------------------------------------------------
__global__ __launch_bounds__(256) void wpgz(
    const float* __restrict__ wat, const float* __restrict__ wpr,
    const float* __restrict__ wsu, const float* __restrict__ wsm,
    const float* __restrict__ wdf, u16* __restrict__ ws) {
  const int b = blockIdx.x, t = threadIdx.x;
  if (b < 32) {
    const int s = b & 7, mat = b >> 3, n = t;
    const float* Wa = (mat == 0) ? wat : (mat == 1) ? wpr : (mat == 2) ? wsm : wsu;
    const float* Wb = (mat == 0) ? wat : (mat == 1) ? wsu : (mat == 2) ? wdf : wdf;
    const float c1  = (mat == 0) ? 0.f : (mat == 3) ? 1.f : -1.f;
    u16 hbuf[32], lbuf[32];
#pragma unroll 8
    for (int k = 0; k < 32; ++k) {
      float v = Wa[(s * 32 + k) * 256 + n] + c1 * Wb[(s * 32 + k) * 256 + n];
      if (mat == 0) { hbuf[k] = bfh(v); lbuf[k] = bfh(v - bup(hbuf[k])); }
      else          { hbuf[k] = bfrn(v); }
    }
    u16* dh = ws + ((mat == 0) ? WH0o : (WRo + (size_t)(mat - 1) * 65536))
               + (size_t)s * 8192 + n * 32;
#pragma unroll
    for (int p = 0; p < 4; ++p) *(uint4*)(dh + p * 8) = ((const uint4*)hbuf)[p];
    if (mat == 0) {
      u16* dl = ws + WL0o + (size_t)s * 8192 + n * 32;
#pragma unroll
      for (int p = 0; p < 4; ++p) *(uint4*)(dl + p * 8) = ((const uint4*)lbuf)[p];
    }
  } else {
    int g = (b - 32) * 256 + t;                    // 24576 threads
    int r = g >> 13, rem = g & 8191;
    int d = rem >> 5, p = rem & 31;
    size_t base = ST0 + (size_t)r * STMAT + (size_t)d * STROW;
    size_t off = (p < 16) ? (base + p * 4) : (base + 16448 + (p - 16) * 4);
    *(ushort4*)(ws + off) = make_ushort4(0, 0, 0, 0);
  }
}

// ---------------------------------------------------------------------------
// gemmS: combined supports S1..S3 (mats 1-3 only; y_att moved into fused).
// C tile 64 x 256/block; single bf16 MFMA; transposed S^T epilogue.
// ---------------------------------------------------------------------------
__global__ __launch_bounds__(512) void gemmS(u16* __restrict__ ws) {
  __shared__ __align__(16) u16 Ahs[2048];            // [64][32]
  __shared__ __align__(16) u16 BU[20480];            // B chunk | Ct[256][80]

  const int t = threadIdx.x, row0 = blockIdx.x * 64;
  const int w = t >> 6, ln = t & 15, quad = (t & 63) >> 4, q8 = quad * 8;
  const int n2base = w * 32;
  const u16* Wh = ws + WRo + (size_t)blockIdx.y * 65536;
  const u16* xr = ws + XRo;

  floatx4 acc[4][2];
#pragma unroll
  for (int m = 0; m < 4; ++m)
#pragma unroll
    for (int n2 = 0; n2 < 2; ++n2) acc[m][n2] = (floatx4){0.f, 0.f, 0.f, 0.f};

  for (int s = 0; s < 8; ++s) {
    if (t < 256) {
      int arow = t >> 2, apart = (t & 3) * 8;
      *(uint4*)(Ahs + arow * 32 + apart) =
          *(const uint4*)(xr + (size_t)(row0 + arow) * 256 + s * 32 + apart);
    }
#pragma unroll
    for (int cc = 0; cc < 2; ++cc) {
      int c = t + 512 * cc;
      *(uint4*)(BU + c * 8) = *(const uint4*)(Wh + (size_t)s * 8192 + c * 8);
    }
    __syncthreads();

    short8 ah[4];
#pragma unroll
    for (int m = 0; m < 4; ++m)
      ah[m] = *(const short8*)(Ahs + (m * 16 + ln) * 32 + q8);
    short8 bh[2];
#pragma unroll
    for (int n2 = 0; n2 < 2; ++n2)
      bh[n2] = *(const short8*)(BU + (n2base + n2 * 16 + ln) * 32 + q8);
#pragma unroll
    for (int m = 0; m < 4; ++m)
#pragma unroll
      for (int n2 = 0; n2 < 2; ++n2)
        acc[m][n2] = __builtin_amdgcn_mfma_f32_16x16x32_bf16(ah[m], bh[n2], acc[m][n2], 0, 0, 0);
    __syncthreads();
  }

  // transposed epilogue via Ct[256 d][80]
#pragma unroll
  for (int m = 0; m < 4; ++m)
#pragma unroll
    for (int n2 = 0; n2 < 2; ++n2) {
      int col = n2base + n2 * 16 + ln;
      ushort4 pk = make_ushort4(bfrn(acc[m][n2][0]), bfrn(acc[m][n2][1]),
                                bfrn(acc[m][n2][2]), bfrn(acc[m][n2][3]));
      *(ushort4*)(BU + col * 80 + m * 16 + quad * 4) = pk;
    }
  __syncthreads();
  u16* STm = ws + ST0 + (size_t)blockIdx.y * STMAT;
#pragma unroll
  for (int cc = 0; cc < 4; ++cc) {
    int c = t + 512 * cc;
    int d = c >> 3, part = c & 7;
    *(uint4*)(STm + (size_t)d * STROW + 64 + row0 + part * 8) =
        *(const uint4*)(BU + d * 80 + part * 8);
  }
}

// ---------------------------------------------------------------------------
// fused_attn: 32 utterances/block, 256 thr, grid 512 (2 blocks/CU).
// ph0: Y = x@W_att (split 3-MFMA, direct global frags) -> LDS.
// ph1: P = Y.Xwin^T (barrier-free K-loop, direct global B-frags).
// softmax in registers (+2 small LDS exchanges); 3 masked bf16 A-images.
// ph2: H = Ap@S1+Asm@S2+Af@S3 (barrier-free: ds_read A, global B-frags).
// log_softmax cross-wave; fp32 out.
// ---------------------------------------------------------------------------
__global__ __launch_bounds__(256) void fused_attn(
    const u16* __restrict__ ws, const int* __restrict__ spk,
    float* __restrict__ out)
{
  __shared__ __align__(16) u16 Yh[32 * YST], Yl[32 * YST];
  __shared__ __align__(16) u16 Am[3 * 32 * AST];
  __shared__ float prt[32][4];
  __shared__ float lsx[32][4];
  __shared__ int spkw[WIN];

  const int t    = threadIdx.x;
  const int w    = t >> 6;
  const int ln   = t & 15;
  const int quad = (t & 63) >> 4;
  const int q8   = quad * 8;
  const int i0   = blockIdx.x * 32;

  if (t < WIN) spkw[t] = spk[min(max(i0 - 64 + t, 0), NU - 1)];

  // ---------------- Phase 0: Y = x @ W_att ----------------
  const int n0 = w * 64;
  floatx4 acc0[2][4];
#pragma unroll
  for (int m = 0; m < 2; ++m)
#pragma unroll
    for (int nt = 0; nt < 4; ++nt) acc0[m][nt] = (floatx4){0.f, 0.f, 0.f, 0.f};

  for (int s = 0; s < 8; ++s) {
    short8 ah[2], al[2];
#pragma unroll
    for (int m = 0; m < 2; ++m) {
      size_t ro = (size_t)(i0 + m * 16 + ln) * DIM + s * 32 + q8;
      ah[m] = *(const short8*)(ws + XHo + ro);
      al[m] = *(const short8*)(ws + XLo + ro);
    }
    short8 bh[4], bl[4];
#pragma unroll
    for (int nt = 0; nt < 4; ++nt) {
      size_t bo = (size_t)s * 8192 + (n0 + nt * 16 + ln) * 32 + q8;
      bh[nt] = *(const short8*)(ws + WH0o + bo);
      bl[nt] = *(const short8*)(ws + WL0o + bo);
    }
#pragma unroll
    for (int m = 0; m < 2; ++m)
#pragma unroll
      for (int nt = 0; nt < 4; ++nt) {
        acc0[m][nt] = __builtin_amdgcn_mfma_f32_16x16x32_bf16(ah[m], bh[nt], acc0[m][nt], 0, 0, 0);
        acc0[m][nt] = __builtin_amdgcn_mfma_f32_16x16x32_bf16(ah[m], bl[nt], acc0[m][nt], 0, 0, 0);
        acc0[m][nt] = __builtin_amdgcn_mfma_f32_16x16x32_bf16(al[m], bh[nt], acc0[m][nt], 0, 0, 0);
      }
  }
#pragma unroll
  for (int m = 0; m < 2; ++m)
#pragma unroll
    for (int nt = 0; nt < 4; ++nt) {
      int col = n0 + nt * 16 + ln;
#pragma unroll
      for (int r = 0; r < 4; ++r) {
        int row = m * 16 + quad * 4 + r;
        float y = acc0[m][nt][r];
        u16 hh = bfh(y);
        Yh[row * YST + col] = hh;
        Yl[row * YST + col] = bfh(y - bup(hh));
      }
    }
  __syncthreads();

  // ---------------- Phase 1: P = Y . Xwin^T ----------------
  const int mrow = w & 1;
  const int ct0  = (w >> 1) * 5;
  const int half = w >> 1;
  floatx4 acc1[5];
#pragma unroll
  for (int cc = 0; cc < 5; ++cc) acc1[cc] = (floatx4){0.f, 0.f, 0.f, 0.f};

  for (int kd = 0; kd < DIM; kd += 32) {
    short8 yh8 = *(const short8*)(Yh + (mrow * 16 + ln) * YST + kd + q8);
    short8 yl8 = *(const short8*)(Yl + (mrow * 16 + ln) * YST + kd + q8);
#pragma unroll
    for (int cc = 0; cc < 5; ++cc) {
      int j  = i0 - 64 + (ct0 + cc) * 16 + ln;
      int jc = min(max(j, 0), NU - 1);
      size_t xo = (size_t)jc * DIM + kd + q8;
      short8 xbh = *(const short8*)(ws + XHo + xo);
      short8 xbl = *(const short8*)(ws + XLo + xo);
      acc1[cc] = __builtin_amdgcn_mfma_f32_16x16x32_bf16(yh8, xbh, acc1[cc], 0, 0, 0);
      acc1[cc] = __builtin_amdgcn_mfma_f32_16x16x32_bf16(yh8, xbl, acc1[cc], 0, 0, 0);
      acc1[cc] = __builtin_amdgcn_mfma_f32_16x16x32_bf16(yl8, xbh, acc1[cc], 0, 0, 0);
    }
  }

  // ---------------- Softmax in registers ----------------
  int  c_of[5];
  bool vj[5];
#pragma unroll
  for (int cc = 0; cc < 5; ++cc) {
    c_of[cc] = (ct0 + cc) * 16 + ln;
    int j = i0 - 64 + c_of[cc];
    vj[cc] = (j >= 0) && (j < NU);
  }
#pragma unroll
  for (int r = 0; r < 4; ++r) {
    int row = mrow * 16 + quad * 4 + r;
    float mx = -3.4e38f;
#pragma unroll
    for (int cc = 0; cc < 5; ++cc) {
      int rel = c_of[cc] - row;
      bool inb = (rel >= 0) && (rel < 128);
      float v = inb ? (vj[cc] ? acc1[cc][r] : 0.f) : -3.4e38f;
      mx = fmaxf(mx, v);
    }
#pragma unroll
    for (int o = 1; o < 16; o <<= 1) mx = fmaxf(mx, __shfl_xor(mx, o));
    if (ln == 0) prt[row][half] = mx;
  }
  __syncthreads();
  float gmax[4], gsum[4];
#pragma unroll
  for (int r = 0; r < 4; ++r) {
    int row = mrow * 16 + quad * 4 + r;
    float gm = fmaxf(prt[row][0], prt[row][1]);
    gmax[r] = gm;
    float s = 0.f;
#pragma unroll
    for (int cc = 0; cc < 5; ++cc) {
      int rel = c_of[cc] - row;
      bool inb = (rel >= 0) && (rel < 128);
      float vv = vj[cc] ? acc1[cc][r] : 0.f;
      float e  = inb ? __expf(vv - gm) : 0.f;
      s += e;                                          // full denominator
      acc1[cc][r] = (inb && vj[cc]) ? e : 0.f;         // numerator for aggregation
    }
#pragma unroll
    for (int o = 1; o < 16; o <<= 1) s += __shfl_xor(s, o);
    if (ln == 0) prt[row][2 + half] = s;
  }
  __syncthreads();
#pragma unroll
  for (int r = 0; r < 4; ++r) {
    int row = mrow * 16 + quad * 4 + r;
    gsum[r] = prt[row][2] + prt[row][3];
  }
  // masked bf16 A-images
#pragma unroll
  for (int r = 0; r < 4; ++r) {
    int row = mrow * 16 + quad * 4 + r;
    float inv = 1.f / gsum[r];
    int myspk = spkw[row + 64];
#pragma unroll
    for (int cc = 0; cc < 5; ++cc) {
      int c = c_of[cc];
      u16 ab = bfrn(acc1[cc][r] * inv);
      Am[(0 * 32 + row) * AST + c] = (c - row >= 64) ? ab : (u16)0;   // pred
      Am[(1 * 32 + row) * AST + c] = (spkw[c] == myspk) ? ab : (u16)0; // same
      Am[(2 * 32 + row) * AST + c] = ab;                               // full
    }
  }
  __syncthreads();

  // ---------------- Phase 2: aggregation (barrier-free) ----------------
  floatx4 acc2[2][4];
#pragma unroll
  for (int m = 0; m < 2; ++m)
#pragma unroll
    for (int nt = 0; nt < 4; ++nt) acc2[m][nt] = (floatx4){0.f, 0.f, 0.f, 0.f};

  for (int kj = 0; kj < WIN; kj += 32) {
#pragma unroll
    for (int rel = 0; rel < 3; ++rel) {
      short8 af[2];
#pragma unroll
      for (int m = 0; m < 2; ++m)
        af[m] = *(const short8*)(Am + (rel * 32 + m * 16 + ln) * AST + kj + q8);
#pragma unroll
      for (int nt = 0; nt < 4; ++nt) {
        size_t so = (size_t)ST0 + (size_t)rel * STMAT
                  + (size_t)(n0 + nt * 16 + ln) * STROW + (i0 + kj) + q8;
        short8 bf8 = *(const short8*)(ws + so);
#pragma unroll
        for (int m = 0; m < 2; ++m)
          acc2[m][nt] = __builtin_amdgcn_mfma_f32_16x16x32_bf16(af[m], bf8, acc2[m][nt], 0, 0, 0);
      }
    }
  }

  // ---------------- log_softmax over 256 dims ----------------
#pragma unroll
  for (int m = 0; m < 2; ++m)
#pragma unroll
    for (int r = 0; r < 4; ++r) {
      float v = fmaxf(fmaxf(acc2[m][0][r], acc2[m][1][r]),
                      fmaxf(acc2[m][2][r], acc2[m][3][r]));
#pragma unroll
      for (int o = 1; o < 16; o <<= 1) v = fmaxf(v, __shfl_xor(v, o));
      if (ln == 0) lsx[m * 16 + quad * 4 + r][w] = v;
    }
  __syncthreads();
#pragma unroll
  for (int m = 0; m < 2; ++m)
#pragma unroll
    for (int r = 0; r < 4; ++r) {
      int row = m * 16 + quad * 4 + r;
      float g = fmaxf(fmaxf(lsx[row][0], lsx[row][1]),
                      fmaxf(lsx[row][2], lsx[row][3]));
      float e = 0.f;
#pragma unroll
      for (int nt = 0; nt < 4; ++nt) e += __expf(acc2[m][nt][r] - g);
#pragma unroll
      for (int o = 1; o < 16; o <<= 1) e += __shfl_xor(e, o);
      if (ln == 0) prt[row][w] = e;
    }
  __syncthreads();
#pragma unroll
  for (int m = 0; m < 2; ++m)
#pragma unroll
    for (int r = 0; r < 4; ++r) {
      int row = m * 16 + quad * 4 + r;
      float g = fmaxf(fmaxf(lsx[row][0], lsx[row][1]),
                      fmaxf(lsx[row][2], lsx[row][3]));
      float lse = g + logf(prt[row][0] + prt[row][1] + prt[row][2] + prt[row][3]);
      size_t rowg = (size_t)(i0 + row) * DIM;
#pragma unroll
      for (int nt = 0; nt < 4; ++nt)
        out[rowg + n0 + nt * 16 + ln] = acc2[m][nt][r] - lse;
    }
}

extern "C" void kernel_launch(void* const* d_in, const int* in_sizes, int n_in,
                              void* d_out, int out_size, void* d_ws, size_t ws_size,
                              hipStream_t stream) {
  const float* x   = (const float*)d_in[0];
  const int*   spk = (const int*)d_in[1];
  const float* wat = (const float*)d_in[2];
  const float* wpr = (const float*)d_in[3];
  const float* wsu = (const float*)d_in[4];
  const float* wsm = (const float*)d_in[5];
  const float* wdf = (const float*)d_in[6];
  float* out = (float*)d_out;
  u16* ws = (u16*)d_ws;    // ~51 MB used

  hipLaunchKernelGGL(xprep, dim3(4096), dim3(256), 0, stream, x, ws);
  hipLaunchKernelGGL(wpgz, dim3(128), dim3(256), 0, stream,
                     wat, wpr, wsu, wsm, wdf, ws);
  hipLaunchKernelGGL(gemmS, dim3(256, 3), dim3(512), 0, stream, ws);
  hipLaunchKernelGGL(fused_attn, dim3(512), dim3(256), 0, stream, ws, spk, out);
}

// Round 6
// 156.185 us; speedup vs baseline: 1.2581x; 1.2581x over previous
//
#include <hip/hip_runtime.h>
#include <hip/hip_bf16.h>

typedef unsigned short u16;
typedef unsigned int u32;
typedef __attribute__((ext_vector_type(8))) short short8;
typedef __attribute__((ext_vector_type(4))) float floatx4;

#define NU 16384
#define DIM 256
#define AMS 208               // Am LDS row stride (u16)

// ws layout (u16 offsets)
#define XHo 0u
#define XLo 4194304u
#define XRo 8388608u
#define YHo 12582912u
#define YLo 16777216u
#define ST0 20971520u
#define STROW 16512u          // 64 guard + 16384 + 64 guard
#define STMAT 4227072u        // 256 * STROW
#define WH0o 33652736u        // ST0 + 3*STMAT
#define WL0o 33718272u
#define WRo  33783808u        // 3 mats x 65536

__device__ __forceinline__ u16 bfh(float v) {            // truncate to bf16
  return (u16)(__float_as_uint(v) >> 16);
}
__device__ __forceinline__ float bup(u16 u) {
  return __uint_as_float(((u32)u) << 16);
}
__device__ __forceinline__ u16 bfrn(float v) {           // round-nearest-even
  u32 u = __float_as_uint(v);
  return (u16)((u + 0x7fffu + ((u >> 16) & 1u)) >> 16);
}

// ---------------------------------------------------------------------------
// xprep: xh/xl (split) + xr (rounded) bf16 copies of x. 8 elems/thread.
// ---------------------------------------------------------------------------
__global__ __launch_bounds__(256) void xprep(const float* __restrict__ x,
                                             u16* __restrict__ ws) {
  int idx = (blockIdx.x * 256 + threadIdx.x) * 8;
  float4 v0 = *(const float4*)(x + idx);
  float4 v1 = *(const float4*)(x + idx + 4);
  float a[8] = {v0.x, v0.y, v0.z, v0.w, v1.x, v1.y, v1.z, v1.w};
  u16 h[8], l[8], r[8];
#pragma unroll
  for (int q = 0; q < 8; ++q) {
    h[q] = bfh(a[q]);
    l[q] = bfh(a[q] - bup(h[q]));
    r[q] = bfrn(a[q]);
  }
  *(uint4*)(ws + XHo + idx) = *(const uint4*)h;
  *(uint4*)(ws + XLo + idx) = *(const uint4*)l;
  *(uint4*)(ws + XRo + idx) = *(const uint4*)r;
}

// ---------------------------------------------------------------------------
// wpgz: blocks 0-31 weight imaging ([s][n][k] order); blocks 32-127 S^T
// guard zeroing.
// ---------------------------------------------------------------------------
__global__ __launch_bounds__(256) void wpgz(
    const float* __restrict__ wat, const float* __restrict__ wpr,
    const float* __restrict__ wsu, const float* __restrict__ wsm,
    const float* __restrict__ wdf, u16* __restrict__ ws) {
  const int b = blockIdx.x, t = threadIdx.x;
  if (b < 32) {
    const int s = b & 7, mat = b >> 3, n = t;
    const float* Wa = (mat == 0) ? wat : (mat == 1) ? wpr : (mat == 2) ? wsm : wsu;
    const float* Wb = (mat == 0) ? wat : (mat == 1) ? wsu : (mat == 2) ? wdf : wdf;
    const float c1  = (mat == 0) ? 0.f : (mat == 3) ? 1.f : -1.f;
    u16 hbuf[32], lbuf[32];
#pragma unroll 8
    for (int k = 0; k < 32; ++k) {
      float v = Wa[(s * 32 + k) * 256 + n] + c1 * Wb[(s * 32 + k) * 256 + n];
      if (mat == 0) { hbuf[k] = bfh(v); lbuf[k] = bfh(v - bup(hbuf[k])); }
      else          { hbuf[k] = bfrn(v); }
    }
    u16* dh = ws + ((mat == 0) ? WH0o : (WRo + (size_t)(mat - 1) * 65536))
               + (size_t)s * 8192 + n * 32;
#pragma unroll
    for (int p = 0; p < 4; ++p) *(uint4*)(dh + p * 8) = ((const uint4*)hbuf)[p];
    if (mat == 0) {
      u16* dl = ws + WL0o + (size_t)s * 8192 + n * 32;
#pragma unroll
      for (int p = 0; p < 4; ++p) *(uint4*)(dl + p * 8) = ((const uint4*)lbuf)[p];
    }
  } else {
    int g = (b - 32) * 256 + t;                    // 24576 threads
    int r = g >> 13, rem = g & 8191;
    int d = rem >> 5, p = rem & 31;
    size_t base = ST0 + (size_t)r * STMAT + (size_t)d * STROW;
    size_t off = (p < 16) ? (base + p * 4) : (base + 16448 + (p - 16) * 4);
    *(ushort4*)(ws + off) = make_ushort4(0, 0, 0, 0);
  }
}

// ---------------------------------------------------------------------------
// gemmS: grid (256, 2). path0: y=x@W_att split 3-MFMA -> yh/yl.
// path1: S1..S3 single-MFMA -> S^T. A-strip staged ONCE (stride 264,
// conflict-free); W fragments read direct from L2-resident images;
// K-loops barrier-free.
// ---------------------------------------------------------------------------
__global__ __launch_bounds__(512) void gemmS(u16* __restrict__ ws) {
  __shared__ __align__(16) u16 U[37888];   // p0: Ah@0 Al@16896 ; p1: Ar@0 Ct@16896

  const int t = threadIdx.x, path = blockIdx.y, row0 = blockIdx.x * 64;
  const int w = t >> 6, ln = t & 15, quad = (t & 63) >> 4, q8 = quad * 8;
  const int n0 = w * 32;

  if (path == 0) {
    // ---- stage xh/xl strip [64][256] -> stride 264 ----
#pragma unroll
    for (int cc = 0; cc < 8; ++cc) {
      int idx = t + 512 * cc;                  // 0..4095
      int buf = idx >> 11, e = idx & 2047;
      int row = e >> 5, c8 = (e & 31) * 8;
      *(uint4*)(U + buf * 16896 + row * 264 + c8) =
          *(const uint4*)(ws + (buf ? XLo : XHo) + (size_t)(row0 + row) * 256 + c8);
    }
    __syncthreads();

    floatx4 acc[4][2];
#pragma unroll
    for (int m = 0; m < 4; ++m)
#pragma unroll
      for (int nt = 0; nt < 2; ++nt) acc[m][nt] = (floatx4){0.f, 0.f, 0.f, 0.f};

    for (int s = 0; s < 8; ++s) {
      short8 ah[4], al[4];
#pragma unroll
      for (int m = 0; m < 4; ++m) {
        ah[m] = *(const short8*)(U + (m * 16 + ln) * 264 + s * 32 + q8);
        al[m] = *(const short8*)(U + 16896 + (m * 16 + ln) * 264 + s * 32 + q8);
      }
      short8 bh[2], bl[2];
#pragma unroll
      for (int nt = 0; nt < 2; ++nt) {
        size_t off = (size_t)s * 8192 + (n0 + nt * 16 + ln) * 32 + q8;
        bh[nt] = *(const short8*)(ws + WH0o + off);
        bl[nt] = *(const short8*)(ws + WL0o + off);
      }
#pragma unroll
      for (int m = 0; m < 4; ++m)
#pragma unroll
        for (int nt = 0; nt < 2; ++nt) {
          acc[m][nt] = __builtin_amdgcn_mfma_f32_16x16x32_bf16(ah[m], bh[nt], acc[m][nt], 0, 0, 0);
          acc[m][nt] = __builtin_amdgcn_mfma_f32_16x16x32_bf16(ah[m], bl[nt], acc[m][nt], 0, 0, 0);
          acc[m][nt] = __builtin_amdgcn_mfma_f32_16x16x32_bf16(al[m], bh[nt], acc[m][nt], 0, 0, 0);
        }
    }
#pragma unroll
    for (int m = 0; m < 4; ++m)
#pragma unroll
      for (int nt = 0; nt < 2; ++nt) {
        int col = n0 + nt * 16 + ln;
#pragma unroll
        for (int r = 0; r < 4; ++r) {
          int row = row0 + m * 16 + quad * 4 + r;
          float y = acc[m][nt][r];
          u16 hh = bfh(y);
          ws[YHo + (size_t)row * 256 + col] = hh;
          ws[YLo + (size_t)row * 256 + col] = bfh(y - bup(hh));
        }
      }
  } else {
    // ---- stage xr strip ----
#pragma unroll
    for (int cc = 0; cc < 4; ++cc) {
      int idx = t + 512 * cc;                  // 0..2047
      int row = idx >> 5, c8 = (idx & 31) * 8;
      *(uint4*)(U + row * 264 + c8) =
          *(const uint4*)(ws + XRo + (size_t)(row0 + row) * 256 + c8);
    }
    __syncthreads();

    for (int mat = 0; mat < 3; ++mat) {
      floatx4 acc[4][2];
#pragma unroll
      for (int m = 0; m < 4; ++m)
#pragma unroll
        for (int nt = 0; nt < 2; ++nt) acc[m][nt] = (floatx4){0.f, 0.f, 0.f, 0.f};
      for (int s = 0; s < 8; ++s) {
        short8 ah[4];
#pragma unroll
        for (int m = 0; m < 4; ++m)
          ah[m] = *(const short8*)(U + (m * 16 + ln) * 264 + s * 32 + q8);
        short8 bh[2];
#pragma unroll
        for (int nt = 0; nt < 2; ++nt)
          bh[nt] = *(const short8*)(ws + WRo + (size_t)mat * 65536
                                    + (size_t)s * 8192 + (n0 + nt * 16 + ln) * 32 + q8);
#pragma unroll
        for (int m = 0; m < 4; ++m)
#pragma unroll
          for (int nt = 0; nt < 2; ++nt)
            acc[m][nt] = __builtin_amdgcn_mfma_f32_16x16x32_bf16(ah[m], bh[nt], acc[m][nt], 0, 0, 0);
      }
      __syncthreads();                           // Ct reuse guard
#pragma unroll
      for (int m = 0; m < 4; ++m)
#pragma unroll
        for (int nt = 0; nt < 2; ++nt) {
          int col = n0 + nt * 16 + ln;
          ushort4 pk = make_ushort4(bfrn(acc[m][nt][0]), bfrn(acc[m][nt][1]),
                                    bfrn(acc[m][nt][2]), bfrn(acc[m][nt][3]));
          *(ushort4*)(U + 16896 + col * 80 + m * 16 + quad * 4) = pk;
        }
      __syncthreads();
      u16* STm = ws + ST0 + (size_t)mat * STMAT;
#pragma unroll
      for (int cc = 0; cc < 4; ++cc) {
        int c = t + 512 * cc;
        int d = c >> 3, part = c & 7;
        *(uint4*)(STm + (size_t)d * STROW + 64 + row0 + part * 8) =
            *(const uint4*)(U + 16896 + d * 80 + part * 8);
      }
    }
  }
}

// ---------------------------------------------------------------------------
// fused_attn: 64 utterances/block, 512 thr, grid 256 (2 blocks/CU, 55KB LDS).
// ph1: P = Y.Xwin^T (X staged per k-step; Y frags direct global; P in regs).
// softmax in registers (2 LDS exchanges); single bf16 A-image in LDS.
// ph2: masked Ac chunks + direct-global S^T B-frags, 24 MFMA/step.
// cross-wave log_softmax; fp32 out.
// ---------------------------------------------------------------------------
__global__ __launch_bounds__(512) void fused_attn(
    const u16* __restrict__ ws, const int* __restrict__ spk,
    float* __restrict__ out)
{
  __shared__ __align__(16) u16 stg[12288];    // ph1: Xh@0 Xl@6144 ; ph2: Ac[3][64][32]
  __shared__ __align__(16) u16 Am[64 * AMS];
  __shared__ int spkw[192];
  __shared__ float prt[64][2], prs[64][2];
  __shared__ float red[64][8];

  const int t    = threadIdx.x;
  const int w    = t >> 6;
  const int ln   = t & 15;
  const int quad = (t & 63) >> 4;
  const int q8   = quad * 8;
  const int i0   = blockIdx.x * 64;
  const int mw   = w & 3;                      // m-frag (16 rows)
  const int half = w >> 2;                     // window col half (96 each)

  if (t < 192) spkw[t] = spk[min(max(i0 - 64 + t, 0), NU - 1)];

  // ---------------- Phase 1: P = Y . Xwin^T ----------------
  floatx4 accP[6];
#pragma unroll
  for (int cc = 0; cc < 6; ++cc) accP[cc] = (floatx4){0.f, 0.f, 0.f, 0.f};

  for (int kd = 0; kd < DIM; kd += 32) {
#pragma unroll
    for (int cc = 0; cc < 3; ++cc) {           // stage X window 192x32 hi/lo
      int idx = t + 512 * cc;                  // 0..1535
      int buf = (idx >= 768) ? 1 : 0;
      int e   = idx - buf * 768;
      int row = e >> 2, c8 = (e & 3) * 8;
      int jc  = min(max(i0 + row - 64, 0), NU - 1);
      *(uint4*)(stg + buf * 6144 + row * 32 + c8) =
          *(const uint4*)(ws + (buf ? XLo : XHo) + (size_t)jc * 256 + kd + c8);
    }
    __syncthreads();

    size_t yo = (size_t)(i0 + mw * 16 + ln) * 256 + kd + q8;
    short8 yh8 = *(const short8*)(ws + YHo + yo);
    short8 yl8 = *(const short8*)(ws + YLo + yo);
#pragma unroll
    for (int cc = 0; cc < 6; ++cc) {
      int xrow = half * 96 + cc * 16 + ln;
      short8 xbh = *(const short8*)(stg + xrow * 32 + q8);
      short8 xbl = *(const short8*)(stg + 6144 + xrow * 32 + q8);
      accP[cc] = __builtin_amdgcn_mfma_f32_16x16x32_bf16(yh8, xbh, accP[cc], 0, 0, 0);
      accP[cc] = __builtin_amdgcn_mfma_f32_16x16x32_bf16(yh8, xbl, accP[cc], 0, 0, 0);
      accP[cc] = __builtin_amdgcn_mfma_f32_16x16x32_bf16(yl8, xbh, accP[cc], 0, 0, 0);
    }
    __syncthreads();
  }

  // ---------------- Softmax in registers ----------------
  int  c_of[6];
  bool vj[6];
#pragma unroll
  for (int cc = 0; cc < 6; ++cc) {
    c_of[cc] = half * 96 + cc * 16 + ln;
    int j = i0 + c_of[cc] - 64;
    vj[cc] = (j >= 0) && (j < NU);
  }
#pragma unroll
  for (int r = 0; r < 4; ++r) {
    int row = mw * 16 + quad * 4 + r;
    float mx = -3.4e38f;
#pragma unroll
    for (int cc = 0; cc < 6; ++cc) {
      int rel = c_of[cc] - row;
      bool inb = (rel >= 0) && (rel < 128);
      if (inb) mx = fmaxf(mx, vj[cc] ? accP[cc][r] : 0.f);
    }
#pragma unroll
    for (int o = 1; o < 16; o <<= 1) mx = fmaxf(mx, __shfl_xor(mx, o));
    if (ln == 0) prt[row][half] = mx;
  }
  __syncthreads();
#pragma unroll
  for (int r = 0; r < 4; ++r) {
    int row = mw * 16 + quad * 4 + r;
    float gm = fmaxf(prt[row][0], prt[row][1]);
    float s = 0.f;
#pragma unroll
    for (int cc = 0; cc < 6; ++cc) {
      int rel = c_of[cc] - row;
      bool inb = (rel >= 0) && (rel < 128);
      float vv = vj[cc] ? accP[cc][r] : 0.f;
      float e  = inb ? __expf(vv - gm) : 0.f;
      s += e;                                      // padded-slot denominator
      accP[cc][r] = (inb && vj[cc]) ? e : 0.f;     // masked numerator
    }
#pragma unroll
    for (int o = 1; o < 16; o <<= 1) s += __shfl_xor(s, o);
    if (ln == 0) prs[row][half] = s;
  }
  __syncthreads();
#pragma unroll
  for (int r = 0; r < 4; ++r) {
    int row = mw * 16 + quad * 4 + r;
    float inv = 1.f / (prs[row][0] + prs[row][1]);
#pragma unroll
    for (int cc = 0; cc < 6; ++cc)
      Am[row * AMS + c_of[cc]] = bfrn(accP[cc][r] * inv);
  }
  __syncthreads();

  // ---------------- Phase 2: aggregation ----------------
  const int n0 = w * 32;
  floatx4 acc2[4][2];
#pragma unroll
  for (int m = 0; m < 4; ++m)
#pragma unroll
    for (int nt = 0; nt < 2; ++nt) acc2[m][nt] = (floatx4){0.f, 0.f, 0.f, 0.f};

  const int arow = t >> 3, aseg = t & 7;
  const int sr = spkw[arow + 64];

  for (int kj = 0; kj < 192; kj += 32) {
    // build masked Ac chunks: [0]=pred, [1]=same, [2]=full
    {
      u16 b0[4], b1[4], b2[4];
#pragma unroll
      for (int q = 0; q < 4; ++q) {
        int c = kj + aseg * 4 + q;
        u16 a = Am[arow * AMS + c];
        b0[q] = (c - arow >= 64) ? a : (u16)0;
        b1[q] = (spkw[c] == sr) ? a : (u16)0;
        b2[q] = a;
      }
      *(ushort4*)(stg + (0 * 64 + arow) * 32 + aseg * 4) = *(const ushort4*)b0;
      *(ushort4*)(stg + (2048 + arow * 32) + aseg * 4)   = *(const ushort4*)b1;
      *(ushort4*)(stg + (4096 + arow * 32) + aseg * 4)   = *(const ushort4*)b2;
    }
    __syncthreads();

#pragma unroll
    for (int rel = 0; rel < 3; ++rel) {
      short8 af[4];
#pragma unroll
      for (int m = 0; m < 4; ++m)
        af[m] = *(const short8*)(stg + rel * 2048 + (m * 16 + ln) * 32 + q8);
#pragma unroll
      for (int nt = 0; nt < 2; ++nt) {
        size_t so = (size_t)ST0 + (size_t)rel * STMAT
                  + (size_t)(n0 + nt * 16 + ln) * STROW + (i0 + kj) + q8;
        short8 bf8 = *(const short8*)(ws + so);
#pragma unroll
        for (int m = 0; m < 4; ++m)
          acc2[m][nt] = __builtin_amdgcn_mfma_f32_16x16x32_bf16(af[m], bf8, acc2[m][nt], 0, 0, 0);
      }
    }
    __syncthreads();
  }

  // ---------------- log_softmax over 256 dims ----------------
#pragma unroll
  for (int m = 0; m < 4; ++m)
#pragma unroll
    for (int r = 0; r < 4; ++r) {
      float v = fmaxf(acc2[m][0][r], acc2[m][1][r]);
#pragma unroll
      for (int o = 1; o < 16; o <<= 1) v = fmaxf(v, __shfl_xor(v, o));
      if (ln == 0) red[m * 16 + quad * 4 + r][w] = v;
    }
  __syncthreads();
  float gmx[4][4];
#pragma unroll
  for (int m = 0; m < 4; ++m)
#pragma unroll
    for (int r = 0; r < 4; ++r) {
      int row = m * 16 + quad * 4 + r;
      float g = red[row][0];
#pragma unroll
      for (int ww = 1; ww < 8; ++ww) g = fmaxf(g, red[row][ww]);
      gmx[m][r] = g;
    }
  __syncthreads();
#pragma unroll
  for (int m = 0; m < 4; ++m)
#pragma unroll
    for (int r = 0; r < 4; ++r) {
      float e = __expf(acc2[m][0][r] - gmx[m][r]) + __expf(acc2[m][1][r] - gmx[m][r]);
#pragma unroll
      for (int o = 1; o < 16; o <<= 1) e += __shfl_xor(e, o);
      if (ln == 0) red[m * 16 + quad * 4 + r][w] = e;
    }
  __syncthreads();
#pragma unroll
  for (int m = 0; m < 4; ++m)
#pragma unroll
    for (int r = 0; r < 4; ++r) {
      int row = m * 16 + quad * 4 + r;
      float s = red[row][0];
#pragma unroll
      for (int ww = 1; ww < 8; ++ww) s += red[row][ww];
      float lse = gmx[m][r] + logf(s);
      size_t rowg = (size_t)(i0 + row) * DIM;
      out[rowg + n0 + ln]      = acc2[m][0][r] - lse;
      out[rowg + n0 + 16 + ln] = acc2[m][1][r] - lse;
    }
}

extern "C" void kernel_launch(void* const* d_in, const int* in_sizes, int n_in,
                              void* d_out, int out_size, void* d_ws, size_t ws_size,
                              hipStream_t stream) {
  const float* x   = (const float*)d_in[0];
  const int*   spk = (const int*)d_in[1];
  const float* wat = (const float*)d_in[2];
  const float* wpr = (const float*)d_in[3];
  const float* wsu = (const float*)d_in[4];
  const float* wsm = (const float*)d_in[5];
  const float* wdf = (const float*)d_in[6];
  float* out = (float*)d_out;
  u16* ws = (u16*)d_ws;    // ~68 MB used

  hipLaunchKernelGGL(xprep, dim3(2048), dim3(256), 0, stream, x, ws);
  hipLaunchKernelGGL(wpgz, dim3(128), dim3(256), 0, stream,
                     wat, wpr, wsu, wsm, wdf, ws);
  hipLaunchKernelGGL(gemmS, dim3(256, 2), dim3(512), 0, stream, ws);
  hipLaunchKernelGGL(fused_attn, dim3(256), dim3(512), 0, stream, ws, spk, out);
}